// Round 7
// baseline (238.299 us; speedup 1.0000x reference)
//
#include <hip/hip_runtime.h>
#include <hip/hip_bf16.h>

// FactorizedTrilinear: out[b,z,x,c,dv] = sum_e p1[b,z,dv,e] p2[b,x,dv,e] p3[b,c,dv,e]
// B=4, Z=128, DV=4, IN=512, R=256. Output 4*128^3*4 fp32 = 134 MB.
// R7: tri holds pv=p2[x-rows] and bq=p3[c-rows] fragments for the FULL K=256 in
// registers (z-invariant!), loops z inside the wave (8 z), and reads the per-z
// uniform p1 row from wave-private LDS (broadcast, no barrier). Fragment L2
// traffic: 32 KB/wave. Wave = 32x x 32c x 8z x 1dv; block = 4 waves = 4 dv
// (same CU -> dv-partial 128B-line writes merge in the local L2).

typedef _Float16 f16;
typedef __attribute__((ext_vector_type(8)))  _Float16 f16x8;
typedef __attribute__((ext_vector_type(4)))  float    f32x4;
typedef __attribute__((ext_vector_type(16))) float    f32x16;

// ---------------- Stage 0: W transpose + f16 convert ----------------
// Wt[mat][n][k] = (f16) W[mat][k][n];  W: [512][256] f32, Wt: [256][512] f16.
__global__ __launch_bounds__(256) void wt_kernel(
    const float* __restrict__ W1, const float* __restrict__ W2, const float* __restrict__ W3,
    f16* __restrict__ Wt) {
    const int mat = blockIdx.z;
    const float* __restrict__ W = (mat == 0) ? W1 : (mat == 1) ? W2 : W3;
    f16* __restrict__ T = Wt + (size_t)mat * 256 * 512;
    const int k0 = blockIdx.x * 64, n0 = blockIdx.y * 64;
    __shared__ float tile[64][65];
    const int t = threadIdx.x;
    const int c = t & 63, r4 = t >> 6;
#pragma unroll
    for (int i = 0; i < 16; ++i) {
        const int k = r4 * 16 + i;
        tile[k][c] = W[(size_t)(k0 + k) * 256 + n0 + c];
    }
    __syncthreads();
#pragma unroll
    for (int i = 0; i < 16; ++i) {
        const int n = r4 * 16 + i;
        T[(size_t)(n0 + n) * 512 + k0 + c] = (f16)tile[c][n];
    }
}

// ---------------- Stage 1: projections via 16x16x32 f16 MFMA ----------------
// GEMM per matrix: M=2048 (m = b*512 + z*4 + dv), N=256, K=512.
// Wave tile 16m x 16n; block 4 waves = 16m x 64n; grid (128,4,3) = 1536 blocks
// -> 6144 waves (6/SIMD). K fully unrolled, no LDS/barriers.
__global__ __launch_bounds__(256, 4) void proj_kernel(
    const float* __restrict__ x1, const float* __restrict__ x2, const float* __restrict__ x3,
    const f16* __restrict__ Wt,
    const float* __restrict__ b1, const float* __restrict__ b2, const float* __restrict__ b3,
    f16* __restrict__ p1, f16* __restrict__ p2, f16* __restrict__ p3) {
    const int mat = blockIdx.z;
    const float* __restrict__ x    = (mat == 0) ? x1 : (mat == 1) ? x2 : x3;
    const f16*   __restrict__ T    = Wt + (size_t)mat * 131072;
    const float* __restrict__ bias = (mat == 0) ? b1 : (mat == 1) ? b2 : b3;
    f16* __restrict__ p = (mat == 0) ? p1 : (mat == 1) ? p2 : p3;

    const int tid  = threadIdx.x;
    const int lane = tid & 63;
    const int w    = tid >> 6;
    const int ln   = lane & 15;
    const int kq   = lane >> 4;
    const int m0   = blockIdx.x * 16;
    const int n    = blockIdx.y * 64 + w * 16 + ln;

    f32x4 acc = (f32x4){0.f, 0.f, 0.f, 0.f};
    const float* Xr = x + (size_t)(m0 + ln) * 512 + kq * 8;
    const f16*   Tr = T + (size_t)n * 512 + kq * 8;

#pragma unroll
    for (int ks = 0; ks < 16; ++ks) {
        f32x4 a0 = *(const f32x4*)(Xr + ks * 32);
        f32x4 a1 = *(const f32x4*)(Xr + ks * 32 + 4);
        f16x8 bv = *(const f16x8*)(Tr + ks * 32);
        f16x8 av;
        av[0] = (f16)a0[0]; av[1] = (f16)a0[1]; av[2] = (f16)a0[2]; av[3] = (f16)a0[3];
        av[4] = (f16)a1[0]; av[5] = (f16)a1[1]; av[6] = (f16)a1[2]; av[7] = (f16)a1[3];
        acc = __builtin_amdgcn_mfma_f32_16x16x32_f16(av, bv, acc, 0, 0, 0);
    }

    // C map (verified): row m = (lane>>4)*4 + reg, col n = lane&15.
    const float bn = bias[n];
#pragma unroll
    for (int r = 0; r < 4; ++r) {
        const int m  = m0 + kq * 4 + r;
        const int bb = m >> 9, z = (m >> 2) & 127, dv = m & 3;
        p[((bb * 4 + dv) * 128 + z) * 256 + n] = (f16)(acc[r] + bn);
    }
}

// ---------------- Stage 2: trilinear, register-resident fragments ----------------
// Grid = b(4) x xt(4) x ct(4) x zg(16) = 1024 blocks; block 256 = 4 waves = 4 dv.
// Wave: 32x x 32c x 8z x 1dv. pv[16],bq[16] (full K=256) live in 128 VGPRs for
// the whole wave; per z: 16 uniform LDS broadcast reads + 16 MFMA; acc 16 AGPR.
__global__ __launch_bounds__(256, 2) void tri_kernel(
    const f16* __restrict__ p1, const f16* __restrict__ p2,
    const f16* __restrict__ p3, float* __restrict__ out) {
    const int bi = blockIdx.x;
    const int zg = bi & 15;
    const int ct = (bi >> 4) & 3;
    const int xt = (bi >> 6) & 3;
    const int b  = bi >> 8;

    const int tid  = threadIdx.x;
    const int lane = tid & 63;
    const int w    = tid >> 6;          // = dv
    const int ln   = lane & 31;
    const int kq   = lane >> 5;
    const int x0   = xt * 32;
    const int c0   = ct * 32;
    const int z0   = zg * 8;
    const int sl   = b * 4 + w;

    __shared__ __align__(16) f16 sP1[4][8 * 256];   // 4 KB per wave, wave-private

    // ---- stage this wave's p1 z-rows into its private LDS region (no barrier) ----
#pragma unroll
    for (int i = 0; i < 4; ++i) {
        const int G  = i * 64 + lane;        // granule: 16B
        const int zo = G >> 5, es = G & 31;
        f16x8 v = *(const f16x8*)(p1 + ((sl * 128 + z0 + zo) << 8) + es * 8);
        *(f16x8*)&sP1[w][G * 8] = v;
    }

    // ---- prologue: full-K fragments in registers (z-invariant) ----
    f16x8 pv[16], bq[16];
    const f16* P2r = p2 + ((sl * 128 + x0 + ln) << 8) + kq * 8;
    const f16* P3r = p3 + ((sl * 128 + c0 + ln) << 8) + kq * 8;
#pragma unroll
    for (int ks = 0; ks < 16; ++ks) {
        pv[ks] = *(const f16x8*)(P2r + ks * 16);
        bq[ks] = *(const f16x8*)(P3r + ks * 16);
    }

    // ---- z loop: per z, 16 LDS broadcast reads + 16 MFMA, then store ----
#pragma unroll 1
    for (int zi = 0; zi < 8; ++zi) {
        f32x16 acc;
#pragma unroll
        for (int i = 0; i < 16; ++i) acc[i] = 0.f;

#pragma unroll
        for (int ks = 0; ks < 16; ++ks) {
            f16x8 u = *(const f16x8*)&sP1[w][(zi * 32 + ks * 2 + kq) * 8];  // broadcast
            f16x8 af = u * pv[ks];        // 4x v_pk_mul_f16
            acc = __builtin_amdgcn_mfma_f32_32x32x16_f16(af, bq[ks], acc, 0, 0, 0);
        }

        // C/D map (m74/m101): col=lane&31 -> c, row=(i&3)+8*(i>>2)+4*kq -> x.
        const int z = z0 + zi;
#pragma unroll
        for (int i = 0; i < 16; ++i) {
            const int x = x0 + (i & 3) + 8 * (i >> 2) + 4 * kq;
            const int c = c0 + ln;
            const size_t flat = ((size_t)((b * 128 + z) * 128 + x) * 128 + c) * 4 + w;
            __builtin_nontemporal_store(acc[i], out + flat);
        }
    }
}

extern "C" void kernel_launch(void* const* d_in, const int* in_sizes, int n_in,
                              void* d_out, int out_size, void* d_ws, size_t ws_size,
                              hipStream_t stream) {
    const float* x1 = (const float*)d_in[0];
    const float* x2 = (const float*)d_in[1];
    const float* x3 = (const float*)d_in[2];
    const float* W1 = (const float*)d_in[3];
    const float* b1 = (const float*)d_in[4];
    const float* W2 = (const float*)d_in[5];
    const float* b2 = (const float*)d_in[6];
    const float* W3 = (const float*)d_in[7];
    const float* b3 = (const float*)d_in[8];

    char* ws = (char*)d_ws;
    f16* p1 = (f16*)ws;                            // [16][128][256] f16 = 1 MB
    f16* p2 = (f16*)(ws + (1u << 20));             // 1 MB
    f16* p3 = (f16*)(ws + 2u * (1u << 20));        // 1 MB
    f16* Wt = (f16*)(ws + 3u * (1u << 20));        // 3 x 256 KB

    wt_kernel<<<dim3(8, 4, 3), 256, 0, stream>>>(W1, W2, W3, Wt);
    proj_kernel<<<dim3(128, 4, 3), 256, 0, stream>>>(x1, x2, x3, Wt, b1, b2, b3,
                                                     p1, p2, p3);
    tri_kernel<<<dim3(1024), 256, 0, stream>>>(p1, p2, p3, (float*)d_out);
}

// Round 8
// 64.891 us; speedup vs baseline: 3.6723x; 3.6723x over previous
//
#include <hip/hip_runtime.h>
#include <hip/hip_bf16.h>

// FactorizedTrilinear: out[b,z,x,c,dv] = sum_e p1[b,z,dv,e] p2[b,x,dv,e] p3[b,c,dv,e]
// B=4, Z=128, DV=4, IN=512, R=256. Output 4*128^3*4 fp32 = 134 MB (write-bound).
// R8: tri = R7's register-resident z-invariant fragments (pv/bq full K=256 in
// 128 VGPRs, 32 KB L2 reads/wave) + LDS transpose of acc so stores are
// f32x4-over-dv coalesced (R7's dv-per-wave scalar stores caused 3.3x HBM
// write amplification -> WRITE_SIZE 435 MB; R6's f32x4 pattern was exact).
// proj: W-tile transposed to LDS on the fly (wt kernel folded in; 2 launches).

typedef _Float16 f16;
typedef __attribute__((ext_vector_type(8)))  _Float16 f16x8;
typedef __attribute__((ext_vector_type(4)))  float    f32x4;
typedef __attribute__((ext_vector_type(16))) float    f32x16;

// ---------------- Stage 1: projections via 32x32x16 f16 MFMA ----------------
// GEMM per matrix: M=2048 (m = b*512 + z*4 + dv), N=256, K=512.
// Block 256 thr = 4 waves (2m x 2n) -> tile 64m x 64n; grid (32,4,3).
// Per 32-k chunk: stage W[32k][64n] -> LDS as sWt[n][k] f16 (row stride 40,
// 4-way-max read conflicts), A-frag per-lane direct from x (f32->f16).
__global__ __launch_bounds__(256) void proj_kernel(
    const float* __restrict__ x1, const float* __restrict__ x2, const float* __restrict__ x3,
    const float* __restrict__ W1, const float* __restrict__ b1,
    const float* __restrict__ W2, const float* __restrict__ b2,
    const float* __restrict__ W3, const float* __restrict__ b3,
    f16* __restrict__ p1, f16* __restrict__ p2, f16* __restrict__ p3) {
    const int mat = blockIdx.z;
    const float* __restrict__ x    = (mat == 0) ? x1 : (mat == 1) ? x2 : x3;
    const float* __restrict__ W    = (mat == 0) ? W1 : (mat == 1) ? W2 : W3;
    const float* __restrict__ bias = (mat == 0) ? b1 : (mat == 1) ? b2 : b3;
    f16* __restrict__ p = (mat == 0) ? p1 : (mat == 1) ? p2 : p3;

    const int tid  = threadIdx.x;
    const int lane = tid & 63;
    const int w    = tid >> 6;
    const int ln   = lane & 31;
    const int kq   = lane >> 5;
    const int m0   = blockIdx.x * 64 + (w >> 1) * 32;
    const int n0b  = blockIdx.y * 64;
    const int n0   = n0b + (w & 1) * 32;

    __shared__ f16 sWt[64 * 40];   // [n][k], row stride 40 f16

    f32x16 acc;
#pragma unroll
    for (int i = 0; i < 16; ++i) acc[i] = 0.f;

    const int snn = tid & 63, skk0 = tid >> 6;

#pragma unroll 1
    for (int ch = 0; ch < 16; ++ch) {
        const int k0 = ch * 32;
        // stage W chunk: [32k][64n] -> sWt[n][k] f16
#pragma unroll
        for (int j = 0; j < 8; ++j) {
            const int kk = skk0 + 4 * j;
            sWt[snn * 40 + kk] = (f16)W[(size_t)(k0 + kk) * 256 + n0b + snn];
        }
        __syncthreads();
#pragma unroll
        for (int ks = 0; ks < 2; ++ks) {
            const float* X = x + (size_t)(m0 + ln) * 512 + k0 + ks * 16 + kq * 8;
            f32x4 a0 = *(const f32x4*)X;
            f32x4 a1 = *(const f32x4*)(X + 4);
            f16x8 av;
            av[0] = (f16)a0[0]; av[1] = (f16)a0[1]; av[2] = (f16)a0[2]; av[3] = (f16)a0[3];
            av[4] = (f16)a1[0]; av[5] = (f16)a1[1]; av[6] = (f16)a1[2]; av[7] = (f16)a1[3];
            f16x8 bv = *(const f16x8*)&sWt[((w & 1) * 32 + ln) * 40 + ks * 16 + kq * 8];
            acc = __builtin_amdgcn_mfma_f32_32x32x16_f16(av, bv, acc, 0, 0, 0);
        }
        __syncthreads();
    }

    // C/D map (m74/m101): col = lane&31 -> n, row = (i&3)+8*(i>>2)+4*kq -> m.
    const int n = n0 + ln;
    const float bn = bias[n];
#pragma unroll
    for (int i = 0; i < 16; ++i) {
        const int m  = m0 + (i & 3) + 8 * (i >> 2) + 4 * kq;
        const int bb = m >> 9, z = (m >> 2) & 127, dv = m & 3;
        p[((bb * 4 + dv) * 128 + z) * 256 + n] = (f16)(acc[i] + bn);
    }
}

// ---------------- Stage 2: trilinear, reg-resident frags + LDS transpose ----------------
// Grid = b(4) x xt(4) x ct(4) x zg(16), zg fastest = 1024 blocks; 256 thr,
// 4 waves, wave w = dv. Wave: 32x x 32c x 8z x 1dv.
// pv[16] (p2 x-rows), bq[16] (p3 c-rows): full K=256 in 128 VGPRs, z-invariant.
// Per z: 16 uniform LDS reads (p1) + 64 pk_mul + 16 MFMA; acc -> sT[dv][x][c]
// (stride 33, conflict-free), barrier, all threads read f32x4-over-dv ->
// coalesced 16B nontemporal stores, barrier.
__global__ __launch_bounds__(256, 2) void tri_kernel(
    const f16* __restrict__ p1, const f16* __restrict__ p2,
    const f16* __restrict__ p3, float* __restrict__ out) {
    const int bi = blockIdx.x;
    const int zg = bi & 15;
    const int ct = (bi >> 4) & 3;
    const int xt = (bi >> 6) & 3;
    const int b  = bi >> 8;

    const int tid  = threadIdx.x;
    const int lane = tid & 63;
    const int w    = tid >> 6;          // = dv
    const int ln   = lane & 31;
    const int kq   = lane >> 5;
    const int x0   = xt * 32;
    const int c0   = ct * 32;
    const int z0   = zg * 8;
    const int sl   = b * 4 + w;

    __shared__ __align__(16) f16  sP1[4][8 * 256];   // 16 KB, wave-private p1 rows
    __shared__ float sT[4 * 32 * 33];                 // 16.5 KB transpose buffer

    // ---- stage this wave's p1 z-rows (no barrier needed: wave-private) ----
#pragma unroll
    for (int i = 0; i < 4; ++i) {
        const int G  = i * 64 + lane;
        const int zo = G >> 5, es = G & 31;
        f16x8 v = *(const f16x8*)(p1 + ((sl * 128 + z0 + zo) << 8) + es * 8);
        *(f16x8*)&sP1[w][G * 8] = v;
    }

    // ---- prologue: full-K fragments in registers (z-invariant) ----
    f16x8 pv[16], bq[16];
    const f16* P2r = p2 + ((sl * 128 + x0 + ln) << 8) + kq * 8;
    const f16* P3r = p3 + ((sl * 128 + c0 + ln) << 8) + kq * 8;
#pragma unroll
    for (int ks = 0; ks < 16; ++ks) {
        pv[ks] = *(const f16x8*)(P2r + ks * 16);
        bq[ks] = *(const f16x8*)(P3r + ks * 16);
    }

    const int cl = tid & 31, xg = tid >> 5;

#pragma unroll 1
    for (int zi = 0; zi < 8; ++zi) {
        f32x16 acc;
#pragma unroll
        for (int i = 0; i < 16; ++i) acc[i] = 0.f;

#pragma unroll
        for (int ks = 0; ks < 16; ++ks) {
            f16x8 u = *(const f16x8*)&sP1[w][(zi * 32 + ks * 2 + kq) * 8];  // broadcast
            f16x8 af = u * pv[ks];        // 4x v_pk_mul_f16
            acc = __builtin_amdgcn_mfma_f32_32x32x16_f16(af, bq[ks], acc, 0, 0, 0);
        }

        // ---- acc -> LDS [dv][x][c] (stride 33: conflict-free) ----
#pragma unroll
        for (int i = 0; i < 16; ++i) {
            const int xl = (i & 3) + 8 * (i >> 2) + 4 * kq;
            sT[w * 1056 + xl * 33 + ln] = acc[i];
        }
        __syncthreads();

        // ---- transposed read + coalesced f32x4-over-dv stores ----
        const int z = z0 + zi;
#pragma unroll
        for (int j = 0; j < 4; ++j) {
            const int xl = xg * 4 + j;
            f32x4 v;
            v[0] = sT[0 * 1056 + xl * 33 + cl];
            v[1] = sT[1 * 1056 + xl * 33 + cl];
            v[2] = sT[2 * 1056 + xl * 33 + cl];
            v[3] = sT[3 * 1056 + xl * 33 + cl];
            const size_t idx = (size_t)((b * 128 + z) * 128 + x0 + xl) * 128 + c0 + cl;
            __builtin_nontemporal_store(v, (f32x4*)(out + idx * 4));
        }
        __syncthreads();
    }
}

extern "C" void kernel_launch(void* const* d_in, const int* in_sizes, int n_in,
                              void* d_out, int out_size, void* d_ws, size_t ws_size,
                              hipStream_t stream) {
    const float* x1 = (const float*)d_in[0];
    const float* x2 = (const float*)d_in[1];
    const float* x3 = (const float*)d_in[2];
    const float* W1 = (const float*)d_in[3];
    const float* b1 = (const float*)d_in[4];
    const float* W2 = (const float*)d_in[5];
    const float* b2 = (const float*)d_in[6];
    const float* W3 = (const float*)d_in[7];
    const float* b3 = (const float*)d_in[8];

    char* ws = (char*)d_ws;
    f16* p1 = (f16*)ws;                            // [16][128][256] f16 = 1 MB
    f16* p2 = (f16*)(ws + (1u << 20));             // 1 MB
    f16* p3 = (f16*)(ws + 2u * (1u << 20));        // 1 MB

    proj_kernel<<<dim3(32, 4, 3), 256, 0, stream>>>(x1, x2, x3, W1, b1, W2, b2, W3, b3,
                                                    p1, p2, p3);
    tri_kernel<<<dim3(1024), 256, 0, stream>>>(p1, p2, p3, (float*)d_out);
}